// Round 5
// baseline (154.630 us; speedup 1.0000x reference)
//
#include <hip/hip_runtime.h>

#define DIM   2048
#define NEXP  64
#define NTOK  32768
#define DC    32                 // d-chunk per stage
#define NC    (DIM / DC)         // 64 chunks
#define TB    32                 // tokens per block (4 waves k-split a 32x64 tile)
#define NBLK  (NTOK / TB)        // 1024 blocks -> 4/CU -> 16 waves/CU = 4/SIMD
#define XSTR  36                 // padded xT row stride (16B-aligned, spreads banks)
#define WSZ   (DC * NEXP)        // 2048 floats
#define XOFF  WSZ
#define BUFF  (WSZ + DC * XSTR)  // 3200 floats per buffer
#define DLDS  (2 * BUFF)         // denom scratch

typedef __attribute__((address_space(1))) const void gvoid_t;
typedef __attribute__((address_space(3))) void lvoid_t;
#define GLDS16(g, l) __builtin_amdgcn_global_load_lds((gvoid_t*)(g), (lvoid_t*)(l), 16, 0, 0)

__global__ void zero_denom_kernel(float* __restrict__ denom) {
    denom[threadIdx.x] = 0.0f;
}

// acc[i][0..7] += xs * {wa,wc}
#define FMA_ROW(i, xs)                         \
    acc[i][0] = fmaf((xs), wa.x, acc[i][0]);   \
    acc[i][1] = fmaf((xs), wa.y, acc[i][1]);   \
    acc[i][2] = fmaf((xs), wa.z, acc[i][2]);   \
    acc[i][3] = fmaf((xs), wa.w, acc[i][3]);   \
    acc[i][4] = fmaf((xs), wc.x, acc[i][4]);   \
    acc[i][5] = fmaf((xs), wc.y, acc[i][5]);   \
    acc[i][6] = fmaf((xs), wc.z, acc[i][6]);   \
    acc[i][7] = fmaf((xs), wc.w, acc[i][7]);

__global__ __launch_bounds__(256, 4)
void gate_kernel(const float* __restrict__ x, const float* __restrict__ w,
                 const float* __restrict__ b, float* __restrict__ out,
                 float* __restrict__ denom)
{
    __shared__ float lds[2 * BUFF + NEXP];   // 25856 B

    const int tid  = threadIdx.x;
    const int lane = tid & 63;
    const int wv   = tid >> 6;
    const int tg   = lane >> 3;     // token group (4 tokens each)
    const int eg   = lane & 7;      // expert group (8 experts each)
    const int tok0 = blockIdx.x * TB;

    if (tid < NEXP) lds[DLDS + tid] = 0.0f;

    // x staging: thread -> (token xt, float4-col xj4); 8 f4 per 128B chunk-row
    const int xt  = tid >> 3;            // 0..31 block-local token
    const int xj4 = tid & 7;             // 0..7
    const float* xrow = x + (size_t)(tok0 + xt) * DIM;

    // W chunk (8KB contiguous): direct global->LDS DMA, linear dest
    auto stageW = [&](int bsel, int c) {
        const float* wsrc = w + (size_t)c * WSZ;
        float* base = lds + bsel * BUFF;
#pragma unroll
        for (int i = 0; i < 2; ++i) {
            const int of = i * 1024 + wv * 256 + lane * 4;   // floats, linear in lane
            GLDS16(wsrc + of, base + of);
        }
    };
    auto loadX = [&](float4& xf, int c) {
        xf = *(const float4*)(xrow + c * DC + xj4 * 4);      // coalesced 128B/row
    };
    auto writeX = [&](const float4& xf, int bsel) {
        float* xb = lds + bsel * BUFF + XOFF;
        const int d0 = xj4 * 4;
        xb[(d0 + 0) * XSTR + xt] = xf.x;     // xT[d][t], padded stride
        xb[(d0 + 1) * XSTR + xt] = xf.y;
        xb[(d0 + 2) * XSTR + xt] = xf.z;
        xb[(d0 + 3) * XSTR + xt] = xf.w;
    };

    float acc[4][8];
#pragma unroll
    for (int i = 0; i < 4; ++i)
#pragma unroll
        for (int j = 0; j < 8; ++j) acc[i][j] = 0.0f;

    float4 xf;
    stageW(0, 0); loadX(xf, 0); writeX(xf, 0);
    __syncthreads();

    for (int c = 0; c < NC; ++c) {
        const int cur = c & 1;
        if (c + 1 < NC) { stageW(cur ^ 1, c + 1); loadX(xf, c + 1); }

        // wave's 8-d slice: 4x8 register tile, 3 ds_read_b128 per d
        {
            const float* wb = lds + cur * BUFF;          // W[d][e] stride 64
            const float* xb = wb + XOFF;                 // xT[d][t] stride 36
#pragma unroll
            for (int dd = 0; dd < 8; ++dd) {
                const int d = wv * 8 + dd;
                const float4 xa = *(const float4*)(xb + d * XSTR + tg * 4);
                const float4 wa = *(const float4*)(wb + d * 64 + eg * 8);
                const float4 wc = *(const float4*)(wb + d * 64 + eg * 8 + 4);
                FMA_ROW(0, xa.x)
                FMA_ROW(1, xa.y)
                FMA_ROW(2, xa.z)
                FMA_ROW(3, xa.w)
            }
        }

        if (c + 1 < NC) writeX(xf, cur ^ 1);   // hidden under compute
        __syncthreads();
    }

    // ---- cross-wave k-reduction: 2 tiles [32][64] in dead buffers, two passes
    {
        float* tw = lds + (wv & 1) * 2048;   // tile (wv&1)
        if (wv < 2) {
#pragma unroll
            for (int i = 0; i < 4; ++i) {
                float4 lo = {acc[i][0], acc[i][1], acc[i][2], acc[i][3]};
                float4 hi = {acc[i][4], acc[i][5], acc[i][6], acc[i][7]};
                *(float4*)(tw + (tg * 4 + i) * 64 + eg * 8)     = lo;
                *(float4*)(tw + (tg * 4 + i) * 64 + eg * 8 + 4) = hi;
            }
        }
        __syncthreads();
        if (wv >= 2) {
#pragma unroll
            for (int i = 0; i < 4; ++i) {
                float4* plo = (float4*)(tw + (tg * 4 + i) * 64 + eg * 8);
                float4* phi = (float4*)(tw + (tg * 4 + i) * 64 + eg * 8 + 4);
                float4 lo = *plo, hi = *phi;
                lo.x += acc[i][0]; lo.y += acc[i][1]; lo.z += acc[i][2]; lo.w += acc[i][3];
                hi.x += acc[i][4]; hi.y += acc[i][5]; hi.z += acc[i][6]; hi.w += acc[i][7];
                *plo = lo; *phi = hi;
            }
        }
        __syncthreads();
    }

    // ---- epilogue: wave wv owns tokens [wv*8, wv*8+8), lane = expert
    const float bias = b[lane];
#pragma unroll
    for (int tt = 0; tt < 8; ++tt) {
        const int t = wv * 8 + tt;
        float v = bias + lds[t * 64 + lane] + lds[2048 + t * 64 + lane];

        // wave argmax, FIRST index on ties (matches jnp.argmax)
        float m = v; int mi = lane;
#pragma unroll
        for (int off = 32; off > 0; off >>= 1) {
            float om = __shfl_xor(m, off);
            int   oi = __shfl_xor(mi, off);
            if (om > m || (om == m && oi < mi)) { m = om; mi = oi; }
        }
        float s = __expf(v - m);
#pragma unroll
        for (int off = 32; off > 0; off >>= 1) s += __shfl_xor(s, off);
        const float g = 1.0f / s;   // top-1 gate = exp(0)/sum

        out[(size_t)(tok0 + t) * NEXP + lane] = (lane == mi) ? g : 0.0f;
        if (lane == mi) atomicAdd(&lds[DLDS + lane], g);
    }

    __syncthreads();
    if (tid < NEXP) atomicAdd(&denom[tid], lds[DLDS + tid]);
}

// out[n,e] *= capacity / (denom[e] + eps); zeros stay zero (branch-free)
__global__ __launch_bounds__(256)
void scale_kernel(float* __restrict__ out, const float* __restrict__ denom)
{
    __shared__ float sc[NEXP];
    if (threadIdx.x < NEXP)
        sc[threadIdx.x] = (float)NTOK / (denom[threadIdx.x] + 1e-6f);
    __syncthreads();

    const size_t i = (size_t)blockIdx.x * blockDim.x + threadIdx.x; // float4 idx
    float4 v = ((const float4*)out)[i];
    const int e0 = (int)((i * 4) & (NEXP - 1));
    v.x *= sc[e0]; v.y *= sc[e0 + 1]; v.z *= sc[e0 + 2]; v.w *= sc[e0 + 3];
    ((float4*)out)[i] = v;
}

extern "C" void kernel_launch(void* const* d_in, const int* in_sizes, int n_in,
                              void* d_out, int out_size, void* d_ws, size_t ws_size,
                              hipStream_t stream) {
    const float* x = (const float*)d_in[0];
    const float* w = (const float*)d_in[1];
    const float* b = (const float*)d_in[2];
    float* out   = (float*)d_out;
    float* denom = (float*)d_ws;   // 64 floats

    zero_denom_kernel<<<1, NEXP, 0, stream>>>(denom);
    gate_kernel<<<NBLK, 256, 0, stream>>>(x, w, b, out, denom);
    scale_kernel<<<(NTOK * NEXP / 4) / 256, 256, 0, stream>>>(out, denom);
}